// Round 1
// baseline (539.644 us; speedup 1.0000x reference)
//
#include <hip/hip_runtime.h>
#include <hip/hip_bf16.h>
#include <stdint.h>

// Problem dims
#define BSZ 64
#define NRG 36
#define VD  2048
#define QD  1024
#define CS  512
#define RD  256
#define KP  2080                 // 2052 padded to multiple of 32
#define MR  (BSZ*NRG)            // 2304 projection rows
#define PR  (BSZ*NRG*NRG)        // 82944 relation rows

typedef __bf16 bf16x8 __attribute__((ext_vector_type(8)));
typedef float  f32x4  __attribute__((ext_vector_type(4)));

static __device__ __forceinline__ f32x4 mfma16(bf16x8 a, bf16x8 b, f32x4 c) {
    return __builtin_amdgcn_mfma_f32_16x16x32_bf16(a, b, c, 0, 0, 0);
}

// ---- prep: Xc_bf16 [MR][KP] = [X | pos | 0-pad], bf16 ----
__global__ void k_prep_xc(const float* __restrict__ X, const float* __restrict__ pos,
                          __bf16* __restrict__ Xc) {
    int r = blockIdx.x;
    const float* xr = X + (size_t)r * VD;
    const float* pr = pos + (size_t)r * 4;
    __bf16* o = Xc + (size_t)r * KP;
    for (int c = threadIdx.x; c < KP; c += 256) {
        float v = 0.f;
        if (c < VD) v = xr[c];
        else if (c < VD + 4) v = pr[c - VD];
        o[c] = (__bf16)v;
    }
}

// ---- prep: Wt[n][k] = W[k][n] (bf16, zero-pad k>=K) ----
__global__ void k_prep_wt(const float* __restrict__ W, __bf16* __restrict__ Wt,
                          int K, int N, int Kp) {
    int n = blockIdx.x;
    __bf16* o = Wt + (size_t)n * Kp;
    for (int k = threadIdx.x; k < Kp; k += 256) {
        float v = (k < K) ? W[(size_t)k * N + n] : 0.f;
        o[k] = (__bf16)v;
    }
}

// ---- Qp[b][c] = relu(Q[b]@Wq[:,c] + bq[c])  (fp32, tiny: 67 MFLOP) ----
__global__ void k_qproj(const float* __restrict__ Q, const float* __restrict__ Wq,
                        const float* __restrict__ bq, float* __restrict__ Qp) {
    __shared__ float qs[QD];
    int b = blockIdx.x;
    for (int k = threadIdx.x; k < QD; k += 256) qs[k] = Q[(size_t)b*QD + k];
    __syncthreads();
    for (int c = threadIdx.x; c < CS; c += 256) {
        float acc = bq[c];
        for (int k = 0; k < QD; ++k) acc = fmaf(qs[k], Wq[(size_t)k*CS + c], acc);
        Qp[(size_t)b*CS + c] = fmaxf(acc, 0.f);
    }
}

// ---- generic MFMA GEMM: Out = epilogue(A[M][lda] @ Bt[N][ldb]^T) ----
// MODE: 1 = relu(acc+bias)+Qp -> bf16 (G1: Xs)
//       2 = relu(acc+bias)    -> f32  (G3: final out)
template<int WM, int WN, int NF, int MODE>
__global__ __launch_bounds__(WM*WN*64) void k_gemm(
    const __bf16* __restrict__ A, int lda,
    const __bf16* __restrict__ Bt, int ldb,
    const float* __restrict__ bias,
    const float* __restrict__ Qp,
    void* __restrict__ Out, int ldo, int K)
{
    int lane = threadIdx.x & 63;
    int w    = threadIdx.x >> 6;
    int wm = w % WM, wn = w / WM;
    int m0 = blockIdx.x * (WM*16) + wm*16;
    int n0 = blockIdx.y * (WN*NF*16) + wn*(NF*16);
    int koff = (lane >> 4) * 8;
    const __bf16* ap = A + (size_t)(m0 + (lane & 15)) * lda + koff;

    f32x4 acc[NF] = {};
    for (int k = 0; k < K; k += 32) {
        bf16x8 a = *(const bf16x8*)(ap + k);
        #pragma unroll
        for (int f = 0; f < NF; ++f) {
            const __bf16* bp = Bt + (size_t)(n0 + f*16 + (lane & 15)) * ldb + k + koff;
            bf16x8 b = *(const bf16x8*)bp;
            acc[f] = mfma16(a, b, acc[f]);
        }
    }
    int crow0 = m0 + ((lane >> 4) << 2);
    #pragma unroll
    for (int f = 0; f < NF; ++f) {
        int col = n0 + f*16 + (lane & 15);
        float bs = bias[col];
        #pragma unroll
        for (int r = 0; r < 4; ++r) {
            int row = crow0 + r;
            float v = fmaxf(acc[f][r] + bs, 0.f);
            if (MODE == 1) {
                v += Qp[(size_t)(row / NRG) * CS + col];
                ((__bf16*)Out)[(size_t)row * ldo + col] = (__bf16)v;
            } else {
                ((float*)Out)[(size_t)row * ldo + col] = v;
            }
        }
    }
}

// ---- pair GEMM (G2): A row (b,i,j) = Xs[b,i,:] * Xs[b,j,:], on the fly ----
// H[row][r] = relu(pair_row @ W1 + b1), bf16
template<int WM, int NF>
__global__ __launch_bounds__(WM*64) void k_gemm_pair(
    const __bf16* __restrict__ Xs,   // [MR][CS]
    const __bf16* __restrict__ Bt,   // W1t [RD][CS]
    const float* __restrict__ bias,  // b1
    __bf16* __restrict__ H)          // [PR][RD]
{
    int lane = threadIdx.x & 63;
    int w    = threadIdx.x >> 6;
    int m0 = blockIdx.x * (WM*16) + w*16;
    int row = m0 + (lane & 15);
    int b   = row / (NRG*NRG);
    int rem = row - b*(NRG*NRG);
    int i   = rem / NRG;
    int j   = rem - i*NRG;
    int koff = (lane >> 4) * 8;
    const __bf16* xip = Xs + (size_t)(b*NRG + i) * CS + koff;
    const __bf16* xjp = Xs + (size_t)(b*NRG + j) * CS + koff;

    f32x4 acc[NF] = {};
    for (int k = 0; k < CS; k += 32) {
        bf16x8 xi = *(const bf16x8*)(xip + k);
        bf16x8 xj = *(const bf16x8*)(xjp + k);
        bf16x8 a;
        #pragma unroll
        for (int t = 0; t < 8; ++t) a[t] = (__bf16)((float)xi[t] * (float)xj[t]);
        #pragma unroll
        for (int f = 0; f < NF; ++f) {
            const __bf16* bp = Bt + (size_t)(f*16 + (lane & 15)) * CS + k + koff;
            bf16x8 bfr = *(const bf16x8*)bp;
            acc[f] = mfma16(a, bfr, acc[f]);
        }
    }
    int crow0 = m0 + ((lane >> 4) << 2);
    #pragma unroll
    for (int f = 0; f < NF; ++f) {
        int col = f*16 + (lane & 15);
        float bs = bias[col];
        #pragma unroll
        for (int r = 0; r < 4; ++r) {
            float v = fmaxf(acc[f][r] + bs, 0.f);
            H[(size_t)(crow0 + r) * RD + col] = (__bf16)v;
        }
    }
}

extern "C" void kernel_launch(void* const* d_in, const int* in_sizes, int n_in,
                              void* d_out, int out_size, void* d_ws, size_t ws_size,
                              hipStream_t stream) {
    const float* X   = (const float*)d_in[0];
    const float* Q   = (const float*)d_in[1];
    const float* pos = (const float*)d_in[2];
    const float* Wv  = (const float*)d_in[3];
    const float* bv  = (const float*)d_in[4];
    const float* Wq  = (const float*)d_in[5];
    const float* bq  = (const float*)d_in[6];
    const float* W1  = (const float*)d_in[7];
    const float* b1  = (const float*)d_in[8];
    const float* W2  = (const float*)d_in[9];
    const float* b2  = (const float*)d_in[10];

    char* ws = (char*)d_ws;
    size_t off = 0;
    auto alloc = [&](size_t bytes) {
        char* p = ws + off;
        off = (off + bytes + 255) & ~(size_t)255;
        return p;
    };
    __bf16* Xc  = (__bf16*)alloc((size_t)MR * KP * 2);   // 9.6 MB
    __bf16* Wvt = (__bf16*)alloc((size_t)CS * KP * 2);   // 2.1 MB
    __bf16* W1t = (__bf16*)alloc((size_t)RD * CS * 2);   // 256 KB
    __bf16* W2t = (__bf16*)alloc((size_t)RD * RD * 2);   // 128 KB
    float*  Qp  = (float*) alloc((size_t)BSZ * CS * 4);  // 128 KB
    __bf16* Xs  = (__bf16*)alloc((size_t)MR * CS * 2);   // 2.4 MB
    __bf16* H   = (__bf16*)alloc((size_t)PR * RD * 2);   // 42.5 MB

    hipLaunchKernelGGL(k_prep_xc, dim3(MR), dim3(256), 0, stream, X, pos, Xc);
    hipLaunchKernelGGL(k_prep_wt, dim3(CS), dim3(256), 0, stream, Wv, Wvt, VD + 4, CS, KP);
    hipLaunchKernelGGL(k_prep_wt, dim3(RD), dim3(256), 0, stream, W1, W1t, CS, RD, CS);
    hipLaunchKernelGGL(k_prep_wt, dim3(RD), dim3(256), 0, stream, W2, W2t, RD, RD, RD);
    hipLaunchKernelGGL(k_qproj,  dim3(BSZ), dim3(256), 0, stream, Q, Wq, bq, Qp);

    // G1: Xs = relu(Xc@Wv + bv) + Qp ; M=2304, K=2080, N=512 ; 32x256 per block
    hipLaunchKernelGGL((k_gemm<2, 2, 8, 1>), dim3(MR/32, 2), dim3(256), 0, stream,
                       Xc, KP, Wvt, KP, bv, Qp, (void*)Xs, CS, KP);
    // G2: H = relu(pair@W1 + b1) ; M=82944, K=512, N=256 ; 64x256 per block
    hipLaunchKernelGGL((k_gemm_pair<4, 16>), dim3(PR/64), dim3(256), 0, stream,
                       Xs, W1t, b1, H);
    // G3: out = relu(H@W2 + b2) ; M=82944, K=256, N=256 ; 64x256 per block
    hipLaunchKernelGGL((k_gemm<4, 1, 16, 2>), dim3(PR/64, 1), dim3(256), 0, stream,
                       H, RD, W2t, RD, b2, nullptr, d_out, RD, RD);
}

// Round 2
// 193.248 us; speedup vs baseline: 2.7925x; 2.7925x over previous
//
#include <hip/hip_runtime.h>
#include <hip/hip_bf16.h>
#include <stdint.h>

#define BSZ 64
#define NRG 36
#define VD  2048
#define QD  1024
#define CS  512
#define RD  256
#define KP  2080                 // 2052 padded to 32
#define MR  (BSZ*NRG)            // 2304
#define TRI  666                 // upper-triangle pairs incl diagonal per batch
#define TRIP 672                 // padded to multiple of 16
#define MTRI (BSZ*TRIP)          // 43008 compacted relation rows

typedef __bf16 bf16x8 __attribute__((ext_vector_type(8)));
typedef float  f32x4  __attribute__((ext_vector_type(4)));

static __device__ __forceinline__ f32x4 mfma16(bf16x8 a, bf16x8 b, f32x4 c) {
    return __builtin_amdgcn_mfma_f32_16x16x32_bf16(a, b, c, 0, 0, 0);
}

// async global->LDS, 16B per lane (dest must be wave-uniform base + lane*16)
static __device__ __forceinline__ void load_lds16(const __bf16* g, __bf16* l) {
    __builtin_amdgcn_global_load_lds(
        (const __attribute__((address_space(1))) uint32_t*)(const void*)g,
        (__attribute__((address_space(3))) uint32_t*)(void*)l,
        16, 0, 0);
}

// ---- triangular index LUT: t -> (i<<8|j), i<=j ----
__global__ void k_lut(int* __restrict__ lut) {
    int t = threadIdx.x;
    if (t >= TRIP) return;
    int tt = (t < TRI) ? t : (TRI - 1);
    int i = 0;
    while (tt >= NRG - i) { tt -= NRG - i; ++i; }
    lut[t] = (i << 8) | (i + tt);
}

// ---- prep: Xc_bf16 [MR][KP] = [X | pos | 0-pad] ----
__global__ void k_prep_xc(const float* __restrict__ X, const float* __restrict__ pos,
                          __bf16* __restrict__ Xc) {
    int r = blockIdx.x;
    const float* xr = X + (size_t)r * VD;
    const float* pr = pos + (size_t)r * 4;
    __bf16* o = Xc + (size_t)r * KP;
    for (int c = threadIdx.x; c < KP; c += 256) {
        float v = 0.f;
        if (c < VD) v = xr[c];
        else if (c < VD + 4) v = pr[c - VD];
        o[c] = (__bf16)v;
    }
}

// ---- prep: Wt[n][k] = W[k][n] (bf16, zero-pad k>=K) ----
__global__ void k_prep_wt(const float* __restrict__ W, __bf16* __restrict__ Wt,
                          int K, int N, int Kp) {
    int n = blockIdx.x;
    __bf16* o = Wt + (size_t)n * Kp;
    for (int k = threadIdx.x; k < Kp; k += 256) {
        float v = (k < K) ? W[(size_t)k * N + n] : 0.f;
        o[k] = (__bf16)v;
    }
}

// ---- Qp[b][c] = relu(Q[b]@Wq[:,c] + bq[c]) fp32 ----
__global__ void k_qproj(const float* __restrict__ Q, const float* __restrict__ Wq,
                        const float* __restrict__ bq, float* __restrict__ Qp) {
    __shared__ float qs[QD];
    int b = blockIdx.x;
    for (int k = threadIdx.x; k < QD; k += 256) qs[k] = Q[(size_t)b*QD + k];
    __syncthreads();
    for (int c = threadIdx.x; c < CS; c += 256) {
        float a0 = 0, a1 = 0, a2 = 0, a3 = 0;
        for (int k = 0; k < QD; k += 4) {
            a0 = fmaf(qs[k],     Wq[(size_t)(k)*CS + c], a0);
            a1 = fmaf(qs[k+1],   Wq[(size_t)(k+1)*CS + c], a1);
            a2 = fmaf(qs[k+2],   Wq[(size_t)(k+2)*CS + c], a2);
            a3 = fmaf(qs[k+3],   Wq[(size_t)(k+3)*CS + c], a3);
        }
        Qp[(size_t)b*CS + c] = fmaxf(a0 + a1 + a2 + a3 + bq[c], 0.f);
    }
}

// ---- tiled MFMA GEMM (m97 structure) ----
// MODE 1: relu(acc+bias)+Qp[b] -> bf16 (G1: Xs).   rows are b*NRG+i
// MODE 2: relu(acc+bias) -> f32, triangular dual-store (G3: out)
// MODE 3: relu(acc+bias) -> bf16 (G2: H, compacted rows)
// PAIR 1: A-fragments generated on the fly as Xs[i]*Xs[j] (compacted rows)
template<int WM, int WN, int FM, int FN, int MODE, int PAIR>
__global__ __launch_bounds__(WM*WN*64)
void k_mm(const __bf16* __restrict__ A, int lda,
          const __bf16* __restrict__ Bt, int ldb,
          const float* __restrict__ bias,
          const float* __restrict__ Qp,
          void* __restrict__ Out, int ldo, int K,
          const int* __restrict__ lut)
{
    constexpr int BM  = WM*FM*16;
    constexpr int BN  = WN*FN*16;
    constexpr int NTH = WM*WN*64;
    constexpr int ACH = PAIR ? 0 : BM*4;   // 16B chunks per A k-tile
    constexpr int BCH = BN*4;

    __shared__ __align__(16) __bf16 sA[PAIR ? 16 : BM*32];
    __shared__ __align__(16) __bf16 sB[BN*32];

    const int tid  = threadIdx.x;
    const int lane = tid & 63;
    const int w    = tid >> 6;
    const int wm   = w % WM;
    const int wn   = w / WM;
    const int m_blk = blockIdx.x * BM;
    const int n_blk = blockIdx.y * BN;
    const int l15  = lane & 15;
    const int l4   = lane >> 4;
    const int koff = l4 * 8;

    const __bf16* xpi[PAIR ? FM : 1];
    const __bf16* xpj[PAIR ? FM : 1];
    if (PAIR) {
        #pragma unroll
        for (int f = 0; f < FM; ++f) {
            int r  = m_blk + wm*FM*16 + f*16 + l15;
            int b  = r / TRIP;
            int t  = r - b*TRIP;
            int ij = lut[t];
            int i  = ij >> 8, j = ij & 255;
            xpi[f] = A + (size_t)(b*NRG + i)*CS + koff;
            xpj[f] = A + (size_t)(b*NRG + j)*CS + koff;
        }
    }

    f32x4 acc[FM][FN] = {};

    const int nkt = K >> 5;
    for (int kt = 0; kt < nkt; ++kt) {
        if (!PAIR) {
            #pragma unroll
            for (int it = 0; it < (ACH + NTH - 1) / NTH; ++it) {
                int t = tid + it*NTH;
                int row = t >> 2, cc = (t & 3) * 8;
                load_lds16(A + (size_t)(m_blk + row)*lda + kt*32 + cc,
                           sA + t*8);
            }
        }
        #pragma unroll
        for (int it = 0; it < BCH / NTH; ++it) {
            int t = tid + it*NTH;
            int row = t >> 2, cc = (t & 3) * 8;
            load_lds16(Bt + (size_t)(n_blk + row)*ldb + kt*32 + cc,
                       sB + t*8);
        }
        __syncthreads();

        bf16x8 af[FM];
        #pragma unroll
        for (int f = 0; f < FM; ++f) {
            if (PAIR) {
                bf16x8 xi = *(const bf16x8*)(xpi[f] + kt*32);
                bf16x8 xj = *(const bf16x8*)(xpj[f] + kt*32);
                #pragma unroll
                for (int t = 0; t < 8; ++t)
                    af[f][t] = (__bf16)((float)xi[t] * (float)xj[t]);
            } else {
                af[f] = *(const bf16x8*)(sA + (wm*FM*16 + f*16 + l15)*32 + koff);
            }
        }
        #pragma unroll
        for (int g = 0; g < FN; ++g) {
            bf16x8 bfr = *(const bf16x8*)(sB + (wn*FN*16 + g*16 + l15)*32 + koff);
            #pragma unroll
            for (int f = 0; f < FM; ++f)
                acc[f][g] = mfma16(af[f], bfr, acc[f][g]);
        }
        __syncthreads();
    }

    // epilogue
    if (MODE == 1 || MODE == 3) {
        #pragma unroll
        for (int f = 0; f < FM; ++f) {
            int row0 = m_blk + wm*FM*16 + f*16 + l4*4;
            #pragma unroll
            for (int g = 0; g < FN; ++g) {
                int col = n_blk + wn*FN*16 + g*16 + l15;
                float bs = bias[col];
                #pragma unroll
                for (int r = 0; r < 4; ++r) {
                    int row = row0 + r;
                    float v = fmaxf(acc[f][g][r] + bs, 0.f);
                    if (MODE == 1) v += Qp[(size_t)(row / NRG)*CS + col];
                    ((__bf16*)Out)[(size_t)row*ldo + col] = (__bf16)v;
                }
            }
        }
    } else {  // MODE 2: triangular dual-store, f32
        #pragma unroll
        for (int f = 0; f < FM; ++f) {
            int row0 = m_blk + wm*FM*16 + f*16 + l4*4;
            #pragma unroll
            for (int r = 0; r < 4; ++r) {
                int row = row0 + r;
                int b = row / TRIP;
                int t = row - b*TRIP;
                if (t < TRI) {
                    int ij = lut[t];
                    int i = ij >> 8, j = ij & 255;
                    size_t o1 = ((size_t)((b*NRG + i)*NRG + j)) * RD;
                    size_t o2 = ((size_t)((b*NRG + j)*NRG + i)) * RD;
                    #pragma unroll
                    for (int g = 0; g < FN; ++g) {
                        int col = n_blk + wn*FN*16 + g*16 + l15;
                        float v = fmaxf(acc[f][g][r] + bias[col], 0.f);
                        ((float*)Out)[o1 + col] = v;
                        ((float*)Out)[o2 + col] = v;
                    }
                }
            }
        }
    }
}

extern "C" void kernel_launch(void* const* d_in, const int* in_sizes, int n_in,
                              void* d_out, int out_size, void* d_ws, size_t ws_size,
                              hipStream_t stream) {
    const float* X   = (const float*)d_in[0];
    const float* Q   = (const float*)d_in[1];
    const float* pos = (const float*)d_in[2];
    const float* Wv  = (const float*)d_in[3];
    const float* bv  = (const float*)d_in[4];
    const float* Wq  = (const float*)d_in[5];
    const float* bq  = (const float*)d_in[6];
    const float* W1  = (const float*)d_in[7];
    const float* b1  = (const float*)d_in[8];
    const float* W2  = (const float*)d_in[9];
    const float* b2  = (const float*)d_in[10];

    char* ws = (char*)d_ws;
    size_t off = 0;
    auto alloc = [&](size_t bytes) {
        char* p = ws + off;
        off = (off + bytes + 255) & ~(size_t)255;
        return p;
    };
    __bf16* Xc  = (__bf16*)alloc((size_t)MR * KP * 2);
    __bf16* Wvt = (__bf16*)alloc((size_t)CS * KP * 2);
    __bf16* W1t = (__bf16*)alloc((size_t)RD * CS * 2);
    __bf16* W2t = (__bf16*)alloc((size_t)RD * RD * 2);
    float*  Qp  = (float*) alloc((size_t)BSZ * CS * 4);
    __bf16* Xs  = (__bf16*)alloc((size_t)MR * CS * 2);
    __bf16* H   = (__bf16*)alloc((size_t)MTRI * RD * 2);
    int*    lut = (int*)   alloc((size_t)TRIP * 4);

    hipLaunchKernelGGL(k_lut,     dim3(1),   dim3(TRIP), 0, stream, lut);
    hipLaunchKernelGGL(k_prep_xc, dim3(MR),  dim3(256), 0, stream, X, pos, Xc);
    hipLaunchKernelGGL(k_prep_wt, dim3(CS),  dim3(256), 0, stream, Wv, Wvt, VD + 4, CS, KP);
    hipLaunchKernelGGL(k_prep_wt, dim3(RD),  dim3(256), 0, stream, W1, W1t, CS, RD, CS);
    hipLaunchKernelGGL(k_prep_wt, dim3(RD),  dim3(256), 0, stream, W2, W2t, RD, RD, RD);
    hipLaunchKernelGGL(k_qproj,   dim3(BSZ), dim3(256), 0, stream, Q, Wq, bq, Qp);

    // G1: Xs = relu(Xc@Wvt^T + bv) + Qp ; 64x64 tiles
    hipLaunchKernelGGL((k_mm<2,2,2,2,1,0>), dim3(MR/64, CS/64), dim3(256), 0, stream,
                       Xc, KP, Wvt, KP, bv, Qp, (void*)Xs, CS, KP, (const int*)lut);
    // G2: H[tri] = relu(pair@W1t^T + b1) ; 128x128 tiles, A on the fly
    hipLaunchKernelGGL((k_mm<2,2,4,4,3,1>), dim3(MTRI/128, RD/128), dim3(256), 0, stream,
                       Xs, CS, W1t, CS, b1, nullptr, (void*)H, RD, CS, (const int*)lut);
    // G3: out = relu(H@W2t^T + b2) ; 128x128 tiles, dual-store (i,j)/(j,i)
    hipLaunchKernelGGL((k_mm<2,2,4,4,2,0>), dim3(MTRI/128, RD/128), dim3(256), 0, stream,
                       H, RD, W2t, RD, b2, nullptr, d_out, RD, RD, (const int*)lut);
}

// Round 3
// 153.452 us; speedup vs baseline: 3.5167x; 1.2593x over previous
//
#include <hip/hip_runtime.h>
#include <hip/hip_bf16.h>
#include <stdint.h>

#define BSZ 64
#define NRG 36
#define VD  2048
#define QD  1024
#define CS  512
#define RD  256
#define KP  2080                 // 2052 padded to 32
#define MR  (BSZ*NRG)            // 2304
#define TRI  666                 // upper-triangle pairs incl diagonal per batch
#define TRIP 672                 // padded to multiple of 16
#define MTRI (BSZ*TRIP)          // 43008 compacted relation rows

typedef __bf16 bf16x8 __attribute__((ext_vector_type(8)));
typedef float  f32x4  __attribute__((ext_vector_type(4)));

static __device__ __forceinline__ f32x4 mfma16(bf16x8 a, bf16x8 b, f32x4 c) {
    return __builtin_amdgcn_mfma_f32_16x16x32_bf16(a, b, c, 0, 0, 0);
}

// async global->LDS, 16B per lane (dest must be wave-uniform base + lane*16)
static __device__ __forceinline__ void load_lds16(const __bf16* g, __bf16* l) {
    __builtin_amdgcn_global_load_lds(
        (const __attribute__((address_space(1))) uint32_t*)(const void*)g,
        (__attribute__((address_space(3))) uint32_t*)(void*)l,
        16, 0, 0);
}

// ---- triangular index LUT: t -> (i<<8|j), i<=j ----
__global__ void k_lut(int* __restrict__ lut) {
    int t = threadIdx.x;
    if (t >= TRIP) return;
    int tt = (t < TRI) ? t : (TRI - 1);
    int i = 0;
    while (tt >= NRG - i) { tt -= NRG - i; ++i; }
    lut[t] = (i << 8) | (i + tt);
}

// ---- prep: Xc_bf16 [MR][KP] = [X | pos | 0-pad] ----
__global__ void k_prep_xc(const float* __restrict__ X, const float* __restrict__ pos,
                          __bf16* __restrict__ Xc) {
    int r = blockIdx.x;
    const float* xr = X + (size_t)r * VD;
    const float* pr = pos + (size_t)r * 4;
    __bf16* o = Xc + (size_t)r * KP;
    for (int c = threadIdx.x; c < KP; c += 256) {
        float v = 0.f;
        if (c < VD) v = xr[c];
        else if (c < VD + 4) v = pr[c - VD];
        o[c] = (__bf16)v;
    }
}

// ---- prep: Wt[n][k] = W[k][n] (bf16, zero-pad k>=K) ----
__global__ void k_prep_wt(const float* __restrict__ W, __bf16* __restrict__ Wt,
                          int K, int N, int Kp) {
    int n = blockIdx.x;
    __bf16* o = Wt + (size_t)n * Kp;
    for (int k = threadIdx.x; k < Kp; k += 256) {
        float v = (k < K) ? W[(size_t)k * N + n] : 0.f;
        o[k] = (__bf16)v;
    }
}

// ---- Qp[b][c] = relu(Q[b]@Wq[:,c] + bq[c]) fp32, split-K parallel ----
// grid (BSZ, CS/64), block 256: 4 K-slices x 64 cols
__global__ __launch_bounds__(256) void k_qproj(
    const float* __restrict__ Q, const float* __restrict__ Wq,
    const float* __restrict__ bq, float* __restrict__ Qp) {
    int b   = blockIdx.x;
    int col = blockIdx.y * 64 + (threadIdx.x & 63);
    int ks  = threadIdx.x >> 6;          // 0..3, 256 k each
    const float* q = Q  + (size_t)b * QD + ks * 256;
    const float* w = Wq + (size_t)(ks * 256) * CS + col;
    float acc = 0.f;
    #pragma unroll 8
    for (int k = 0; k < 256; ++k)
        acc = fmaf(q[k], w[(size_t)k * CS], acc);
    __shared__ float red[256];
    red[threadIdx.x] = acc;
    __syncthreads();
    if (ks == 0) {
        float v = red[threadIdx.x] + red[threadIdx.x + 64]
                + red[threadIdx.x + 128] + red[threadIdx.x + 192] + bq[col];
        Qp[(size_t)b * CS + col] = fmaxf(v, 0.f);
    }
}

// ---- tiled MFMA GEMM (m97 structure) ----
// MODE 1: relu(acc+bias)+Qp[b] -> bf16 (G1: Xs).   rows are b*NRG+i
// MODE 2: relu(acc+bias) -> f32, triangular dual-store (G3: out)
// MODE 3: relu(acc+bias) -> bf16 (G2: H, compacted rows)
// PAIR 1: A-fragments generated on the fly as Xs[i]*Xs[j] (compacted rows)
template<int WM, int WN, int FM, int FN, int MODE, int PAIR>
__global__ __launch_bounds__(WM*WN*64)
void k_mm(const __bf16* __restrict__ A, int lda,
          const __bf16* __restrict__ Bt, int ldb,
          const float* __restrict__ bias,
          const float* __restrict__ Qp,
          void* __restrict__ Out, int ldo, int K,
          const int* __restrict__ lut)
{
    constexpr int BM  = WM*FM*16;
    constexpr int BN  = WN*FN*16;
    constexpr int NTH = WM*WN*64;
    constexpr int ACH = PAIR ? 0 : BM*4;   // 16B chunks per A k-tile
    constexpr int BCH = BN*4;

    __shared__ __align__(16) __bf16 sA[PAIR ? 16 : BM*32];
    __shared__ __align__(16) __bf16 sB[BN*32];

    const int tid  = threadIdx.x;
    const int lane = tid & 63;
    const int w    = tid >> 6;
    const int wm   = w % WM;
    const int wn   = w / WM;
    const int m_blk = blockIdx.x * BM;
    const int n_blk = blockIdx.y * BN;
    const int l15  = lane & 15;
    const int l4   = lane >> 4;
    const int koff = l4 * 8;

    const __bf16* xpi[PAIR ? FM : 1];
    const __bf16* xpj[PAIR ? FM : 1];
    if (PAIR) {
        #pragma unroll
        for (int f = 0; f < FM; ++f) {
            int r  = m_blk + wm*FM*16 + f*16 + l15;
            int b  = r / TRIP;
            int t  = r - b*TRIP;
            int ij = lut[t];
            int i  = ij >> 8, j = ij & 255;
            xpi[f] = A + (size_t)(b*NRG + i)*CS + koff;
            xpj[f] = A + (size_t)(b*NRG + j)*CS + koff;
        }
    }

    f32x4 acc[FM][FN] = {};

    const int nkt = K >> 5;
    for (int kt = 0; kt < nkt; ++kt) {
        if (!PAIR) {
            #pragma unroll
            for (int it = 0; it < (ACH + NTH - 1) / NTH; ++it) {
                int t = tid + it*NTH;
                int row = t >> 2, cc = (t & 3) * 8;
                load_lds16(A + (size_t)(m_blk + row)*lda + kt*32 + cc,
                           sA + t*8);
            }
        }
        #pragma unroll
        for (int it = 0; it < BCH / NTH; ++it) {
            int t = tid + it*NTH;
            int row = t >> 2, cc = (t & 3) * 8;
            load_lds16(Bt + (size_t)(n_blk + row)*ldb + kt*32 + cc,
                       sB + t*8);
        }
        __syncthreads();

        bf16x8 af[FM];
        #pragma unroll
        for (int f = 0; f < FM; ++f) {
            if (PAIR) {
                bf16x8 xi = *(const bf16x8*)(xpi[f] + kt*32);
                bf16x8 xj = *(const bf16x8*)(xpj[f] + kt*32);
                #pragma unroll
                for (int t = 0; t < 8; ++t)
                    af[f][t] = (__bf16)((float)xi[t] * (float)xj[t]);
            } else {
                af[f] = *(const bf16x8*)(sA + (wm*FM*16 + f*16 + l15)*32 + koff);
            }
        }
        #pragma unroll
        for (int g = 0; g < FN; ++g) {
            bf16x8 bfr = *(const bf16x8*)(sB + (wn*FN*16 + g*16 + l15)*32 + koff);
            #pragma unroll
            for (int f = 0; f < FM; ++f)
                acc[f][g] = mfma16(af[f], bfr, acc[f][g]);
        }
        __syncthreads();
    }

    // epilogue
    if (MODE == 1 || MODE == 3) {
        #pragma unroll
        for (int f = 0; f < FM; ++f) {
            int row0 = m_blk + wm*FM*16 + f*16 + l4*4;
            #pragma unroll
            for (int g = 0; g < FN; ++g) {
                int col = n_blk + wn*FN*16 + g*16 + l15;
                float bs = bias[col];
                #pragma unroll
                for (int r = 0; r < 4; ++r) {
                    int row = row0 + r;
                    float v = fmaxf(acc[f][g][r] + bs, 0.f);
                    if (MODE == 1) v += Qp[(size_t)(row / NRG)*CS + col];
                    ((__bf16*)Out)[(size_t)row*ldo + col] = (__bf16)v;
                }
            }
        }
    } else {  // MODE 2: triangular dual-store, f32
        #pragma unroll
        for (int f = 0; f < FM; ++f) {
            int row0 = m_blk + wm*FM*16 + f*16 + l4*4;
            #pragma unroll
            for (int r = 0; r < 4; ++r) {
                int row = row0 + r;
                int b = row / TRIP;
                int t = row - b*TRIP;
                if (t < TRI) {
                    int ij = lut[t];
                    int i = ij >> 8, j = ij & 255;
                    size_t o1 = ((size_t)((b*NRG + i)*NRG + j)) * RD;
                    size_t o2 = ((size_t)((b*NRG + j)*NRG + i)) * RD;
                    #pragma unroll
                    for (int g = 0; g < FN; ++g) {
                        int col = n_blk + wn*FN*16 + g*16 + l15;
                        float v = fmaxf(acc[f][g][r] + bias[col], 0.f);
                        ((float*)Out)[o1 + col] = v;
                        ((float*)Out)[o2 + col] = v;
                    }
                }
            }
        }
    }
}

extern "C" void kernel_launch(void* const* d_in, const int* in_sizes, int n_in,
                              void* d_out, int out_size, void* d_ws, size_t ws_size,
                              hipStream_t stream) {
    const float* X   = (const float*)d_in[0];
    const float* Q   = (const float*)d_in[1];
    const float* pos = (const float*)d_in[2];
    const float* Wv  = (const float*)d_in[3];
    const float* bv  = (const float*)d_in[4];
    const float* Wq  = (const float*)d_in[5];
    const float* bq  = (const float*)d_in[6];
    const float* W1  = (const float*)d_in[7];
    const float* b1  = (const float*)d_in[8];
    const float* W2  = (const float*)d_in[9];
    const float* b2  = (const float*)d_in[10];

    char* ws = (char*)d_ws;
    size_t off = 0;
    auto alloc = [&](size_t bytes) {
        char* p = ws + off;
        off = (off + bytes + 255) & ~(size_t)255;
        return p;
    };
    __bf16* Xc  = (__bf16*)alloc((size_t)MR * KP * 2);
    __bf16* Wvt = (__bf16*)alloc((size_t)CS * KP * 2);
    __bf16* W1t = (__bf16*)alloc((size_t)RD * CS * 2);
    __bf16* W2t = (__bf16*)alloc((size_t)RD * RD * 2);
    float*  Qp  = (float*) alloc((size_t)BSZ * CS * 4);
    __bf16* Xs  = (__bf16*)alloc((size_t)MR * CS * 2);
    __bf16* H   = (__bf16*)alloc((size_t)MTRI * RD * 2);
    int*    lut = (int*)   alloc((size_t)TRIP * 4);

    hipLaunchKernelGGL(k_lut,     dim3(1),   dim3(TRIP), 0, stream, lut);
    hipLaunchKernelGGL(k_prep_xc, dim3(MR),  dim3(256), 0, stream, X, pos, Xc);
    hipLaunchKernelGGL(k_prep_wt, dim3(CS),  dim3(256), 0, stream, Wv, Wvt, VD + 4, CS, KP);
    hipLaunchKernelGGL(k_prep_wt, dim3(RD),  dim3(256), 0, stream, W1, W1t, CS, RD, CS);
    hipLaunchKernelGGL(k_prep_wt, dim3(RD),  dim3(256), 0, stream, W2, W2t, RD, RD, RD);
    hipLaunchKernelGGL(k_qproj,   dim3(BSZ, CS/64), dim3(256), 0, stream, Q, Wq, bq, Qp);

    // G1: Xs = relu(Xc@Wvt^T + bv) + Qp ; 64x64 tiles
    hipLaunchKernelGGL((k_mm<2,2,2,2,1,0>), dim3(MR/64, CS/64), dim3(256), 0, stream,
                       Xc, KP, Wvt, KP, bv, Qp, (void*)Xs, CS, KP, (const int*)lut);
    // G2: H[tri] = relu(pair@W1t^T + b1) ; 128x128 tiles, A on the fly
    hipLaunchKernelGGL((k_mm<2,2,4,4,3,1>), dim3(MTRI/128, RD/128), dim3(256), 0, stream,
                       Xs, CS, W1t, CS, b1, nullptr, (void*)H, RD, CS, (const int*)lut);
    // G3: out = relu(H@W2t^T + b2) ; 128x128 tiles, dual-store (i,j)/(j,i)
    hipLaunchKernelGGL((k_mm<2,2,4,4,2,0>), dim3(MTRI/128, RD/128), dim3(256), 0, stream,
                       H, RD, W2t, RD, b2, nullptr, d_out, RD, RD, (const int*)lut);
}

// Round 4
// 120.782 us; speedup vs baseline: 4.4679x; 1.2705x over previous
//
#include <hip/hip_runtime.h>
#include <hip/hip_bf16.h>
#include <stdint.h>

#define BSZ 64
#define NRG 36
#define VD  2048
#define QD  1024
#define CS  512
#define RD  256
#define KP  2080                 // 2052 padded to 32
#define MR  (BSZ*NRG)            // 2304
#define TRI  666                 // upper-triangle pairs (i<=j) per batch
#define TRIQ 768                 // padded per-batch rows: 12 chunks of 64

typedef __bf16 bf16x8 __attribute__((ext_vector_type(8)));
typedef float  f32x4  __attribute__((ext_vector_type(4)));

static __device__ __forceinline__ f32x4 mfma16(bf16x8 a, bf16x8 b, f32x4 c) {
    return __builtin_amdgcn_mfma_f32_16x16x32_bf16(a, b, c, 0, 0, 0);
}

// async global->LDS, 16B per lane (dest = wave-uniform base + lane*16)
static __device__ __forceinline__ void load_lds16(const __bf16* g, __bf16* l) {
    __builtin_amdgcn_global_load_lds(
        (const __attribute__((address_space(1))) uint32_t*)(const void*)g,
        (__attribute__((address_space(3))) uint32_t*)(void*)l,
        16, 0, 0);
}

// ---- triangular index LUT: t -> (i<<8|j), i<=j, clamped past TRI ----
__global__ void k_lut(int* __restrict__ lut) {
    int t = threadIdx.x;
    if (t >= TRIQ) return;
    int tt = (t < TRI) ? t : (TRI - 1);
    int i = 0;
    while (tt >= NRG - i) { tt -= NRG - i; ++i; }
    lut[t] = (i << 8) | (i + tt);
}

// ---- prep: Xc_bf16 [MR][KP] = [X | pos | 0-pad] (row-major) ----
__global__ void k_prep_xc(const float* __restrict__ X, const float* __restrict__ pos,
                          __bf16* __restrict__ Xc) {
    int r = blockIdx.x;
    const float* xr = X + (size_t)r * VD;
    const float* pr = pos + (size_t)r * 4;
    __bf16* o = Xc + (size_t)r * KP;
    for (int c = threadIdx.x; c < KP; c += 256) {
        float v = 0.f;
        if (c < VD) v = xr[c];
        else if (c < VD + 4) v = pr[c - VD];
        o[c] = (__bf16)v;
    }
}

// ---- prep: g-major weight layout Wg[k/8][N][8] <- W[k][n], zero-pad k>=K ----
// grid (N/64, Kp/32), block 256. Coalesced reads AND writes.
__global__ __launch_bounds__(256) void k_prep_wg(
    const float* __restrict__ W, __bf16* __restrict__ Wg, int K, int N) {
    int g = blockIdx.y * 4 + (threadIdx.x >> 6);
    int n = blockIdx.x * 64 + (threadIdx.x & 63);
    bf16x8 v;
    #pragma unroll
    for (int e = 0; e < 8; ++e) {
        int k = g * 8 + e;
        v[e] = (__bf16)((k < K) ? W[(size_t)k * N + n] : 0.f);
    }
    *(bf16x8*)(Wg + ((size_t)g * N + n) * 8) = v;
}

// ---- Qp[b][c] = relu(Q[b]@Wq[:,c] + bq[c]) fp32, split-K parallel ----
__global__ __launch_bounds__(256) void k_qproj(
    const float* __restrict__ Q, const float* __restrict__ Wq,
    const float* __restrict__ bq, float* __restrict__ Qp) {
    int b   = blockIdx.x;
    int col = blockIdx.y * 64 + (threadIdx.x & 63);
    int ks  = threadIdx.x >> 6;
    const float* q = Q  + (size_t)b * QD + ks * 256;
    const float* w = Wq + (size_t)(ks * 256) * CS + col;
    float acc = 0.f;
    #pragma unroll 8
    for (int k = 0; k < 256; ++k)
        acc = fmaf(q[k], w[(size_t)k * CS], acc);
    __shared__ float red[256];
    red[threadIdx.x] = acc;
    __syncthreads();
    if (ks == 0) {
        float v = red[threadIdx.x] + red[threadIdx.x + 64]
                + red[threadIdx.x + 128] + red[threadIdx.x + 192] + bq[col];
        Qp[(size_t)b * CS + col] = fmaxf(v, 0.f);
    }
}

// ---- G1: Xs = relu(Xc @ Wv + bv) + Qp[b]  (64x64 tiles, bf16 out) ----
__global__ __launch_bounds__(256) void k_g1(
    const __bf16* __restrict__ Xc,   // [MR][KP]
    const __bf16* __restrict__ Wvg,  // g-major [KP/8][CS][8]
    const float* __restrict__ bv,
    const float* __restrict__ Qp,    // [BSZ][CS]
    __bf16* __restrict__ Xs)         // [MR][CS]
{
    __shared__ __align__(16) __bf16 sA[64 * 32];     // [row][32k]
    __shared__ __align__(16) __bf16 sB[4 * 64 * 8];  // [l4][64n][8]

    const int tid = threadIdx.x;
    const int lane = tid & 63;
    const int w = tid >> 6;
    const int wm = w & 1, wn = w >> 1;
    const int l15 = lane & 15, l4 = lane >> 4;
    const int m0 = blockIdx.x * 64;
    const int n0 = blockIdx.y * 64;

    f32x4 acc[2][2] = {};
    for (int kt = 0; kt < KP / 32; ++kt) {
        {   // A tile: 256 chunks of 16B
            int row = tid >> 2, cc = (tid & 3) * 8;
            load_lds16(Xc + (size_t)(m0 + row) * KP + kt * 32 + cc, sA + tid * 8);
            // B tile: [l4][64][8]
            load_lds16(Wvg + ((size_t)(kt * 4 + (tid >> 6)) * CS + n0 + (tid & 63)) * 8,
                       sB + tid * 8);
        }
        __syncthreads();
        bf16x8 af[2], bf[2];
        #pragma unroll
        for (int f = 0; f < 2; ++f)
            af[f] = *(const bf16x8*)(sA + (wm * 32 + f * 16 + l15) * 32 + l4 * 8);
        #pragma unroll
        for (int g = 0; g < 2; ++g)
            bf[g] = *(const bf16x8*)(sB + ((size_t)l4 * 64 + wn * 32 + g * 16 + l15) * 8);
        #pragma unroll
        for (int f = 0; f < 2; ++f)
            #pragma unroll
            for (int g = 0; g < 2; ++g)
                acc[f][g] = mfma16(af[f], bf[g], acc[f][g]);
        __syncthreads();
    }
    #pragma unroll
    for (int f = 0; f < 2; ++f) {
        int row0 = m0 + wm * 32 + f * 16 + l4 * 4;
        #pragma unroll
        for (int g = 0; g < 2; ++g) {
            int col = n0 + wn * 32 + g * 16 + l15;
            float bb = bv[col];
            #pragma unroll
            for (int r = 0; r < 4; ++r) {
                int row = row0 + r;
                float v = fmaxf(acc[f][g][r] + bb, 0.f) + Qp[(size_t)(row / NRG) * CS + col];
                Xs[(size_t)row * CS + col] = (__bf16)v;
            }
        }
    }
}

// ---- fused G2+G3: per (batch, 64-row tri-chunk) ----
// stage1: acc1 = pair @ W1 (K=512) ; H = relu(acc1+b1) -> LDS
// stage2: acc2 = H @ W2 (K=256)    ; out = relu(acc2+b2), dual-store (i,j)/(j,i)
__global__ __launch_bounds__(256, 3) void k_g23(
    const __bf16* __restrict__ Xs,   // [MR][CS]
    const __bf16* __restrict__ W1g,  // [CS/8][RD][8]
    const __bf16* __restrict__ W2g,  // [RD/8][RD][8]
    const float* __restrict__ b1,
    const float* __restrict__ b2,
    float* __restrict__ Out,         // [BSZ][NRG][NRG][RD]
    const int* __restrict__ lut)
{
    __shared__ __align__(16) __bf16 sB[4 * RD * 8];   // 16 KB [l4][256][8]
    __shared__ __align__(16) __bf16 sH[32 * 64 * 8];  // 32 KB [g2][row][8]

    const int tid = threadIdx.x;
    const int lane = tid & 63;
    const int w = tid >> 6;
    const int wm = w & 1, wn = w >> 1;   // wave = 32 rows x 128 cols
    const int l15 = lane & 15, l4 = lane >> 4;
    const int b = blockIdx.y;
    const int r_base = blockIdx.x * 64;  // within padded 768 tri rows

    // pair-row pointers for the 2 M-fragments
    const __bf16* xpi[2];
    const __bf16* xpj[2];
    #pragma unroll
    for (int f = 0; f < 2; ++f) {
        int t = r_base + wm * 32 + f * 16 + l15;
        int ij = lut[t];
        int i = ij >> 8, j = ij & 255;
        xpi[f] = Xs + (size_t)(b * NRG + i) * CS + l4 * 8;
        xpj[f] = Xs + (size_t)(b * NRG + j) * CS + l4 * 8;
    }

    // ---- stage 1: K=512, 16 k-tiles ----
    f32x4 acc[2][8] = {};
    for (int kt = 0; kt < 16; ++kt) {
        #pragma unroll
        for (int it = 0; it < 4; ++it) {
            int c = tid + it * 256;
            load_lds16(W1g + (size_t)kt * (RD * 32) + c * 8, sB + c * 8);
        }
        __syncthreads();
        bf16x8 af[2];
        #pragma unroll
        for (int f = 0; f < 2; ++f) {
            bf16x8 xi = *(const bf16x8*)(xpi[f] + kt * 32);
            bf16x8 xj = *(const bf16x8*)(xpj[f] + kt * 32);
            #pragma unroll
            for (int e = 0; e < 8; ++e)
                af[f][e] = (__bf16)((float)xi[e] * (float)xj[e]);
        }
        #pragma unroll
        for (int g = 0; g < 8; ++g) {
            int col = wn * 128 + g * 16 + l15;
            bf16x8 bfr = *(const bf16x8*)(sB + ((size_t)l4 * RD + col) * 8);
            acc[0][g] = mfma16(af[0], bfr, acc[0][g]);
            acc[1][g] = mfma16(af[1], bfr, acc[1][g]);
        }
        __syncthreads();
    }

    // ---- transition: H = relu(acc+b1) -> sH[g2][row][8] ----
    #pragma unroll
    for (int g = 0; g < 8; ++g) {
        int col = wn * 128 + g * 16 + l15;
        float bb = b1[col];
        int g2 = col >> 3, e = col & 7;
        #pragma unroll
        for (int f = 0; f < 2; ++f) {
            int row0 = wm * 32 + f * 16 + l4 * 4;
            #pragma unroll
            for (int r = 0; r < 4; ++r) {
                float v = fmaxf(acc[f][g][r] + bb, 0.f);
                sH[((size_t)g2 * 64 + row0 + r) * 8 + e] = (__bf16)v;
            }
        }
    }
    __syncthreads();

    // ---- stage 2: K=256, 8 k-tiles ----
    f32x4 acc2[2][8] = {};
    for (int kt = 0; kt < 8; ++kt) {
        #pragma unroll
        for (int it = 0; it < 4; ++it) {
            int c = tid + it * 256;
            load_lds16(W2g + (size_t)kt * (RD * 32) + c * 8, sB + c * 8);
        }
        __syncthreads();
        bf16x8 ah[2];
        #pragma unroll
        for (int f = 0; f < 2; ++f) {
            int row = wm * 32 + f * 16 + l15;
            ah[f] = *(const bf16x8*)(sH + ((size_t)(kt * 4 + l4) * 64 + row) * 8);
        }
        #pragma unroll
        for (int g = 0; g < 8; ++g) {
            int col = wn * 128 + g * 16 + l15;
            bf16x8 bfr = *(const bf16x8*)(sB + ((size_t)l4 * RD + col) * 8);
            acc2[0][g] = mfma16(ah[0], bfr, acc2[0][g]);
            acc2[1][g] = mfma16(ah[1], bfr, acc2[1][g]);
        }
        __syncthreads();
    }

    // ---- epilogue: dual-store fp32 ----
    float bias2[8];
    #pragma unroll
    for (int g = 0; g < 8; ++g) bias2[g] = b2[wn * 128 + g * 16 + l15];
    #pragma unroll
    for (int f = 0; f < 2; ++f) {
        int row_l = wm * 32 + f * 16 + l4 * 4;
        #pragma unroll
        for (int r = 0; r < 4; ++r) {
            int t = r_base + row_l + r;
            if (t < TRI) {
                int ij = lut[t];
                int i = ij >> 8, j = ij & 255;
                float* o1 = Out + (size_t)((b * NRG + i) * NRG + j) * RD;
                float* o2 = Out + (size_t)((b * NRG + j) * NRG + i) * RD;
                #pragma unroll
                for (int g = 0; g < 8; ++g) {
                    int col = wn * 128 + g * 16 + l15;
                    float v = fmaxf(acc2[f][g][r] + bias2[g], 0.f);
                    o1[col] = v;
                    o2[col] = v;
                }
            }
        }
    }
}

extern "C" void kernel_launch(void* const* d_in, const int* in_sizes, int n_in,
                              void* d_out, int out_size, void* d_ws, size_t ws_size,
                              hipStream_t stream) {
    const float* X   = (const float*)d_in[0];
    const float* Q   = (const float*)d_in[1];
    const float* pos = (const float*)d_in[2];
    const float* Wv  = (const float*)d_in[3];
    const float* bv  = (const float*)d_in[4];
    const float* Wq  = (const float*)d_in[5];
    const float* bq  = (const float*)d_in[6];
    const float* W1  = (const float*)d_in[7];
    const float* b1  = (const float*)d_in[8];
    const float* W2  = (const float*)d_in[9];
    const float* b2  = (const float*)d_in[10];

    char* ws = (char*)d_ws;
    size_t off = 0;
    auto alloc = [&](size_t bytes) {
        char* p = ws + off;
        off = (off + bytes + 255) & ~(size_t)255;
        return p;
    };
    __bf16* Xc  = (__bf16*)alloc((size_t)MR * KP * 2);        // 9.6 MB
    __bf16* Wvg = (__bf16*)alloc((size_t)(KP/8) * CS * 8 * 2);// 2.1 MB
    __bf16* W1g = (__bf16*)alloc((size_t)(CS/8) * RD * 8 * 2);// 256 KB
    __bf16* W2g = (__bf16*)alloc((size_t)(RD/8) * RD * 8 * 2);// 128 KB
    float*  Qp  = (float*) alloc((size_t)BSZ * CS * 4);       // 128 KB
    __bf16* Xs  = (__bf16*)alloc((size_t)MR * CS * 2);        // 2.4 MB
    int*    lut = (int*)   alloc((size_t)TRIQ * 4);

    hipLaunchKernelGGL(k_lut,     dim3(1),        dim3(TRIQ), 0, stream, lut);
    hipLaunchKernelGGL(k_prep_xc, dim3(MR),       dim3(256),  0, stream, X, pos, Xc);
    hipLaunchKernelGGL(k_prep_wg, dim3(CS/64, KP/32), dim3(256), 0, stream, Wv, Wvg, VD + 4, CS);
    hipLaunchKernelGGL(k_prep_wg, dim3(RD/64, CS/32), dim3(256), 0, stream, W1, W1g, CS, RD);
    hipLaunchKernelGGL(k_prep_wg, dim3(RD/64, RD/32), dim3(256), 0, stream, W2, W2g, RD, RD);
    hipLaunchKernelGGL(k_qproj,   dim3(BSZ, CS/64),   dim3(256), 0, stream, Q, Wq, bq, Qp);

    hipLaunchKernelGGL(k_g1,  dim3(MR/64, CS/64), dim3(256), 0, stream,
                       Xc, Wvg, bv, Qp, Xs);
    hipLaunchKernelGGL(k_g23, dim3(TRIQ/64, BSZ), dim3(256), 0, stream,
                       Xs, W1g, W2g, b1, b2, (float*)d_out, (const int*)lut);
}